// Round 4
// baseline (135.695 us; speedup 1.0000x reference)
//
#include <hip/hip_runtime.h>
#include <math.h>

#define N_NODES 100000
#define D_INPUT 128
#define FDIM 128
#define A_HEADS 8
#define B_SEGS 512
#define D_OUTPUT 64
#define H_DIM 2304

typedef __attribute__((ext_vector_type(8))) __bf16 bf16x8;
typedef __attribute__((ext_vector_type(4))) float f32x4;

static __device__ inline unsigned short f2bfu(float f) {
    unsigned u = __builtin_bit_cast(unsigned, f);
    u += 0x7fffu + ((u >> 16) & 1u);
    return (unsigned short)(u >> 16);
}
static __device__ inline unsigned packbf(float a, float b) {
    return (unsigned)f2bfu(a) | ((unsigned)f2bfu(b) << 16);
}
static __device__ inline float bfl(unsigned u) {
    unsigned x = u << 16; return __builtin_bit_cast(float, x);
}
static __device__ inline float bfh(unsigned u) {
    unsigned x = u & 0xffff0000u; return __builtin_bit_cast(float, x);
}
static __device__ inline bf16x8 pack8(float4 a, float4 b) {
    union { unsigned u[4]; bf16x8 v; } r;
    r.u[0] = packbf(a.x, a.y); r.u[1] = packbf(a.z, a.w);
    r.u[2] = packbf(b.x, b.y); r.u[3] = packbf(b.z, b.w);
    return r.v;
}
// order-preserving float<->uint for atomicMax
static __device__ inline unsigned fenc(float f) {
    unsigned b = __builtin_bit_cast(unsigned, f);
    return (b & 0x80000000u) ? ~b : (b | 0x80000000u);
}
static __device__ inline float fdec(unsigned k) {
    unsigned b = (k & 0x80000000u) ? (k & 0x7fffffffu) : ~k;
    return __builtin_bit_cast(float, b);
}
#define MAXK_INIT 0x007fffffu   /* fenc(-inf) */

// ---------------- segment boundaries (batch is sorted) ----------------
__global__ void seg_bounds_kernel(const int* __restrict__ batch, int n,
                                  int* __restrict__ seg_start) {
    int b = threadIdx.x;
    if (b > B_SEGS) return;
    int lo = 0, hi = n;
    while (lo < hi) {
        int mid = (lo + hi) >> 1;
        if (batch[mid] < b) lo = mid + 1; else hi = mid;
    }
    seg_start[b] = lo;
}

// --------------- init atomic accumulators (every launch) --------------------
__global__ __launch_bounds__(256) void init_kernel(float* __restrict__ sums,
                                                   unsigned* __restrict__ maxk) {
    int i = blockIdx.x * 256 + threadIdx.x;   // 524288 total
    sums[i] = 0.f;
    maxk[i] = MAXK_INIT;
}

// ------------- one-time weight conversion fp32 -> bf16 (packed u32) ---------
__global__ __launch_bounds__(256) void wconv_kernel(
        const float* __restrict__ W_in, const float* __restrict__ W_a,
        const float* __restrict__ W_out, unsigned* __restrict__ Wb,
        unsigned* __restrict__ Wa, unsigned* __restrict__ Wo) {
    int i = blockIdx.x * 256 + threadIdx.x;
    if (i < 8192) {                       // W_in [128][128] -> [128][64]u32
        float2 v = *(const float2*)(W_in + (size_t)i * 2);
        Wb[i] = packbf(v.x, v.y);
    } else if (i < 9216) {                // W_a padded to 16 rows
        int j = i - 8192;
        if (j < 512) {
            float2 v = *(const float2*)(W_a + (size_t)j * 2);
            Wa[j] = packbf(v.x, v.y);
        } else Wa[j] = 0u;
    } else if (i < 17408) {               // W_out[:, :256] -> [64][128]u32
        int j = i - 9216;
        int row = j >> 7, cu = j & 127;
        float2 v = *(const float2*)(W_out + (size_t)row * H_DIM + cu * 2);
        Wo[j] = packbf(v.x, v.y);
    }
}

// ---- mega-fused: xp GEMM + score + out_part GEMM + segment partial sum/max --
// 64-node tile, 4 waves x 16 nodes.
__global__ __launch_bounds__(256) void fused_in_kernel(
        const float* __restrict__ x, const int* __restrict__ batch,
        const float* __restrict__ b_in, const float* __restrict__ b_a,
        const unsigned* __restrict__ Wb, const unsigned* __restrict__ Wa,
        const unsigned* __restrict__ Wo, float* __restrict__ sums,
        unsigned* __restrict__ maxk, unsigned short* __restrict__ out_part) {
    __shared__ __align__(16) unsigned XP[64 * 68];   // xp tile bf16 [64][136]u16
    __shared__ float scoref[64 * 8];
    __shared__ int batch_lds[64];
    unsigned short* XPs = (unsigned short*)XP;
    const int t = threadIdx.x;
    const int w = t >> 6, l = t & 63, lr = l & 15, lk = l >> 4;
    const int n_base = blockIdx.x * 64;
    if (t < 64) {
        int n = n_base + t;
        batch_lds[t] = (n < N_NODES) ? batch[n] : -1;
    }
    const int arow = n_base + w * 16 + lr;
    const int arowc = min(arow, N_NODES - 1);

    const f32x4 z4 = {0.f, 0.f, 0.f, 0.f};
    f32x4 acc[8], aco[4];
#pragma unroll
    for (int nr = 0; nr < 8; ++nr) acc[nr] = z4;
#pragma unroll
    for (int nr = 0; nr < 4; ++nr) aco[nr] = z4;

    bf16x8 af[4];
#pragma unroll
    for (int ks = 0; ks < 4; ++ks) {
        const float4* xp4 = (const float4*)(x + (size_t)arowc * 128 + ks * 32 + lk * 8);
        af[ks] = pack8(xp4[0], xp4[1]);
    }
#pragma unroll
    for (int ks = 0; ks < 4; ++ks) {
#pragma unroll
        for (int nr = 0; nr < 8; ++nr) {
            bf16x8 bfrag = *(const bf16x8*)&Wb[(nr * 16 + lr) * 64 + ks * 16 + lk * 4];
            acc[nr] = __builtin_amdgcn_mfma_f32_16x16x32_bf16(af[ks], bfrag, acc[nr], 0, 0, 0);
        }
#pragma unroll
        for (int nr = 0; nr < 4; ++nr) {   // out_part, x half (K 0..127)
            bf16x8 bo = *(const bf16x8*)&Wo[(nr * 16 + lr) * 128 + ks * 16 + lk * 4];
            aco[nr] = __builtin_amdgcn_mfma_f32_16x16x32_bf16(af[ks], bo, aco[nr], 0, 0, 0);
        }
    }
    // bias + write XP tile (own rows only)
#pragma unroll
    for (int nr = 0; nr < 8; ++nr) {
        float bf = b_in[nr * 16 + lr];
#pragma unroll
        for (int r = 0; r < 4; ++r) {
            int row = w * 16 + lk * 4 + r;
            XPs[row * 136 + nr * 16 + lr] = f2bfu(((const float*)&acc[nr])[r] + bf);
        }
    }
    // score MFMA (A = own 16 rows from LDS; same-wave dependency)
    f32x4 sacc = z4;
#pragma unroll
    for (int ks = 0; ks < 4; ++ks) {
        bf16x8 a = *(const bf16x8*)&XPs[(w * 16 + lr) * 136 + ks * 32 + lk * 8];
        bf16x8 bfrag = *(const bf16x8*)&Wa[lr * 64 + ks * 16 + lk * 4];
        sacc = __builtin_amdgcn_mfma_f32_16x16x32_bf16(a, bfrag, sacc, 0, 0, 0);
    }
    if (lr < A_HEADS) {
        float ba = b_a[lr];
#pragma unroll
        for (int r = 0; r < 4; ++r) {
            int row = w * 16 + lk * 4 + r;
            scoref[row * 8 + lr] = __expf(-fabsf(((const float*)&sacc)[r] + ba));
        }
    }
    // out_part, xp half (K 128..255): A = own XP rows
#pragma unroll
    for (int ks = 0; ks < 4; ++ks) {
        bf16x8 a = *(const bf16x8*)&XPs[(w * 16 + lr) * 136 + ks * 32 + lk * 8];
#pragma unroll
        for (int nr = 0; nr < 4; ++nr) {
            bf16x8 bo = *(const bf16x8*)&Wo[(nr * 16 + lr) * 128 + 64 + ks * 16 + lk * 4];
            aco[nr] = __builtin_amdgcn_mfma_f32_16x16x32_bf16(a, bo, aco[nr], 0, 0, 0);
        }
    }
    // store out_part bf16 (own rows)
#pragma unroll
    for (int nr = 0; nr < 4; ++nr)
#pragma unroll
        for (int r = 0; r < 4; ++r) {
            int n = n_base + w * 16 + lk * 4 + r;
            if (n < N_NODES)
                out_part[(size_t)n * 64 + nr * 16 + lr] = f2bfu(((const float*)&aco[nr])[r]);
        }
    __syncthreads();

    // ---- per-run segment partial sum/max + device atomics ----
    const int a0 = t >> 6;     // heads a0 and a0+4
    const int f2 = t & 63;     // u32 feature pair -> features 2*f2, 2*f2+1
    int n0 = 0;
    while (n0 < 64) {
        int seg = batch_lds[n0];
        int n1 = n0 + 1;
        while (n1 < 64 && batch_lds[n1] == seg) ++n1;
        if (seg >= 0) {
            float s00 = 0.f, s01 = 0.f, s10 = 0.f, s11 = 0.f;
            float m00 = -INFINITY, m01 = -INFINITY, m10 = -INFINITY, m11 = -INFINITY;
            for (int n = n0; n < n1; ++n) {
                unsigned u = XP[n * 68 + f2];
                float x0 = bfl(u), x1 = bfh(u);
                float sa = scoref[n * 8 + a0];
                float sb = scoref[n * 8 + a0 + 4];
                float e00 = sa * x0, e01 = sa * x1;
                float e10 = sb * x0, e11 = sb * x1;
                s00 += e00; s01 += e01; s10 += e10; s11 += e11;
                m00 = fmaxf(m00, e00); m01 = fmaxf(m01, e01);
                m10 = fmaxf(m10, e10); m11 = fmaxf(m11, e11);
            }
            float* sbase = sums + (size_t)seg * 1024;
            atomicAdd(&sbase[a0 * 128 + 2 * f2], s00);
            atomicAdd(&sbase[a0 * 128 + 2 * f2 + 1], s01);
            atomicAdd(&sbase[(a0 + 4) * 128 + 2 * f2], s10);
            atomicAdd(&sbase[(a0 + 4) * 128 + 2 * f2 + 1], s11);
            unsigned* mbase = maxk + (size_t)seg * 1024;
            atomicMax(&mbase[a0 * 128 + 2 * f2], fenc(m00));
            atomicMax(&mbase[a0 * 128 + 2 * f2 + 1], fenc(m01));
            atomicMax(&mbase[(a0 + 4) * 128 + 2 * f2], fenc(m10));
            atomicMax(&mbase[(a0 + 4) * 128 + 2 * f2 + 1], fenc(m11));
        }
        n0 = n1;
    }
}

// ------- finalize segments: mean/max decode + projection through W_out ------
__global__ __launch_bounds__(256) void seg_final_kernel(
        const float* __restrict__ sums, const unsigned* __restrict__ maxk,
        const int* __restrict__ seg_start, const float* __restrict__ W_out,
        const float* __restrict__ b_out, float* __restrict__ agg_proj) {
    __shared__ float agg[8 * 256];
    const int b = blockIdx.x, t = threadIdx.x;
    const int count = seg_start[b + 1] - seg_start[b];
    const float inv = (count > 0) ? 1.f / (float)count : 0.f;
#pragma unroll
    for (int i = 0; i < 4; ++i) {
        int idx = i * 256 + t;            // 0..1023: a = idx>>7, f = idx&127
        int a = idx >> 7, f = idx & 127;
        float sm = sums[(size_t)b * 1024 + idx];
        float mv = (count > 0) ? fdec(maxk[(size_t)b * 1024 + idx]) : 0.f;
        agg[a * 256 + f] = sm * inv;
        agg[a * 256 + 128 + f] = mv;
    }
    __syncthreads();
    const int wave = t >> 6, lane = t & 63;
#pragma unroll
    for (int i = 0; i < 16; ++i) {
        int o = wave * 16 + i;
        const float* wrow = W_out + (size_t)o * H_DIM + 256;
        float partial = 0.f;
#pragma unroll
        for (int c = 0; c < 8; ++c) {
            int jj = c * 256 + lane * 4;
            float4 wv = *(const float4*)&wrow[jj];
            float4 av = *(const float4*)&agg[jj];
            partial = fmaf(wv.x, av.x, partial);
            partial = fmaf(wv.y, av.y, partial);
            partial = fmaf(wv.z, av.z, partial);
            partial = fmaf(wv.w, av.w, partial);
        }
#pragma unroll
        for (int m = 1; m < 64; m <<= 1) partial += __shfl_xor(partial, m);
        if (lane == 0) agg_proj[b * D_OUTPUT + o] = partial + b_out[o];
    }
}

// -------- out = relu(out_part + agg_proj[batch]) — pure streaming -----------
__global__ __launch_bounds__(256) void out_final_kernel(
        const unsigned* __restrict__ out_part, const int* __restrict__ batch,
        const float* __restrict__ agg_proj, float* __restrict__ out) {
    int q = blockIdx.x * 256 + threadIdx.x;   // quad index: N*16 total
    if (q >= N_NODES * 16) return;
    int n = q >> 4, c4 = (q & 15) * 4;
    int bs = batch[n];
    uint2 v = *(const uint2*)(out_part + (size_t)n * 32 + (c4 >> 1));
    float4 ap = *(const float4*)(agg_proj + (size_t)bs * 64 + c4);
    float4 o;
    o.x = fmaxf(bfl(v.x) + ap.x, 0.f);
    o.y = fmaxf(bfh(v.x) + ap.y, 0.f);
    o.z = fmaxf(bfl(v.y) + ap.z, 0.f);
    o.w = fmaxf(bfh(v.y) + ap.w, 0.f);
    *(float4*)(out + (size_t)n * 64 + c4) = o;
}

extern "C" void kernel_launch(void* const* d_in, const int* in_sizes, int n_in,
                              void* d_out, int out_size, void* d_ws, size_t ws_size,
                              hipStream_t stream) {
    const float* x     = (const float*)d_in[0];
    const int*   batch = (const int*)d_in[1];
    const float* W_in  = (const float*)d_in[3];
    const float* b_in  = (const float*)d_in[4];
    const float* W_a   = (const float*)d_in[5];
    const float* b_a   = (const float*)d_in[6];
    const float* W_out = (const float*)d_in[7];
    const float* b_out = (const float*)d_in[8];
    float* out = (float*)d_out;

    float*    sums = (float*)d_ws;                        // 512*1024 f32
    unsigned* maxk = (unsigned*)(sums + 524288);          // 512*1024 u32
    float* agg_proj = (float*)(maxk + 524288);            // 512*64 f32
    unsigned* Wb = (unsigned*)(agg_proj + 32768);         // 128*64
    unsigned* Wa = Wb + 8192;                             // 16*64
    unsigned* Wo = Wa + 1024;                             // 64*128
    int* seg_start = (int*)(Wo + 8192);                   // 513 (pad to 520)
    unsigned short* out_part = (unsigned short*)(seg_start + 520); // N*64 u16
    // view as u32 for vectorized final read
    unsigned* out_part_u32 = (unsigned*)out_part;

    seg_bounds_kernel<<<1, 1024, 0, stream>>>(batch, N_NODES, seg_start);
    wconv_kernel<<<68, 256, 0, stream>>>(W_in, W_a, W_out, Wb, Wa, Wo);
    init_kernel<<<2048, 256, 0, stream>>>(sums, maxk);
    fused_in_kernel<<<(N_NODES + 63) / 64, 256, 0, stream>>>(
        x, batch, b_in, b_a, Wb, Wa, Wo, sums, maxk, out_part);
    seg_final_kernel<<<B_SEGS, 256, 0, stream>>>(
        sums, maxk, seg_start, W_out, b_out, agg_proj);
    out_final_kernel<<<(N_NODES * 16 + 255) / 256, 256, 0, stream>>>(
        out_part_u32, batch, agg_proj, out);
}

// Round 5
// 71.867 us; speedup vs baseline: 1.8881x; 1.8881x over previous
//
#include <hip/hip_runtime.h>
#include <math.h>

#define N_NODES 100000
#define D_INPUT 128
#define FDIM 128
#define A_HEADS 8
#define B_SEGS 512
#define D_OUTPUT 64
#define H_DIM 2304

typedef __attribute__((ext_vector_type(8))) __bf16 bf16x8;
typedef __attribute__((ext_vector_type(4))) float f32x4;

static __device__ inline unsigned short f2bfu(float f) {
    unsigned u = __builtin_bit_cast(unsigned, f);
    u += 0x7fffu + ((u >> 16) & 1u);
    return (unsigned short)(u >> 16);
}
static __device__ inline unsigned packbf(float a, float b) {
    return (unsigned)f2bfu(a) | ((unsigned)f2bfu(b) << 16);
}
static __device__ inline float bfl(unsigned u) {
    unsigned x = u << 16; return __builtin_bit_cast(float, x);
}
static __device__ inline float bfh(unsigned u) {
    unsigned x = u & 0xffff0000u; return __builtin_bit_cast(float, x);
}
static __device__ inline bf16x8 pack8(float4 a, float4 b) {
    union { unsigned u[4]; bf16x8 v; } r;
    r.u[0] = packbf(a.x, a.y); r.u[1] = packbf(a.z, a.w);
    r.u[2] = packbf(b.x, b.y); r.u[3] = packbf(b.z, b.w);
    return r.v;
}

// ---------------- segment boundaries (batch is sorted) ----------------
__global__ void seg_bounds_kernel(const int* __restrict__ batch, int n,
                                  int* __restrict__ seg_start) {
    int b = threadIdx.x;
    if (b > B_SEGS) return;
    int lo = 0, hi = n;
    while (lo < hi) {
        int mid = (lo + hi) >> 1;
        if (batch[mid] < b) lo = mid + 1; else hi = mid;
    }
    seg_start[b] = lo;
}

// ---- segment-major mega kernel: one block per segment, 512 threads ----
// Does: weights->LDS bf16; per 128-row chunk: xp GEMM, score, out_part GEMM,
// register-accumulated segment sum/max; then mean/max -> projection.
__global__ __launch_bounds__(512, 2) void mega_kernel(
        const float* __restrict__ x, const int* __restrict__ seg_start,
        const float* __restrict__ W_in, const float* __restrict__ b_in,
        const float* __restrict__ W_a, const float* __restrict__ b_a,
        const float* __restrict__ W_out, const float* __restrict__ b_out,
        unsigned short* __restrict__ out_part, float* __restrict__ agg_proj) {
    __shared__ __align__(16) unsigned WbL[128 * 68];  // W_in bf16 [f][k/2]
    __shared__ __align__(16) unsigned WoL[64 * 132];  // W_out[:, :256] bf16
    __shared__ __align__(16) unsigned WaL[16 * 68];   // W_a bf16, rows 8..15 = 0
    __shared__ __align__(16) unsigned XP[128 * 68];   // xp chunk bf16 (u16 x136)
    __shared__ float scoref[128 * 8];
    unsigned short* XPs = (unsigned short*)XP;
    float* XPf = (float*)XP;                          // reused for agg at end

    const int b = blockIdx.x;
    const int start = seg_start[b], end = seg_start[b + 1];
    const int cnt = end - start;
    const int t = threadIdx.x;

    if (cnt == 0) {   // agg all zeros -> proj = b_out
        if (t < 64) agg_proj[b * 64 + t] = b_out[t];
        return;
    }

    // ---- stage weights (fp32 -> bf16) ----
#pragma unroll
    for (int i = 0; i < 16; ++i) {                    // W_in: 8192 u32
        int idx = i * 512 + t, row = idx >> 6, c = idx & 63;
        float2 v = *(const float2*)(W_in + (size_t)row * 128 + c * 2);
        WbL[row * 68 + c] = packbf(v.x, v.y);
    }
#pragma unroll
    for (int i = 0; i < 16; ++i) {                    // W_out[:, :256]: 8192 u32
        int idx = i * 512 + t, row = idx >> 7, c = idx & 127;
        float2 v = *(const float2*)(W_out + (size_t)row * H_DIM + c * 2);
        WoL[row * 132 + c] = packbf(v.x, v.y);
    }
    {                                                 // W_a + zero pad
        int row = t >> 6, c = t & 63;
        float2 v = *(const float2*)(W_a + (size_t)row * 128 + c * 2);
        WaL[row * 68 + c] = packbf(v.x, v.y);
        WaL[(row + 8) * 68 + c] = 0u;
    }
    __syncthreads();

    const int w = t >> 6, l = t & 63, lr = l & 15, lk = l >> 4;
    const int a0 = t >> 6;      // head owned in aggregation (== w)
    const int f2 = t & 63;      // feature pair 2*f2, 2*f2+1

    const f32x4 z4 = {0.f, 0.f, 0.f, 0.f};
    float sum0 = 0.f, sum1 = 0.f, mx0 = -INFINITY, mx1 = -INFINITY;

    for (int c0 = start; c0 < end; c0 += 128) {
        const int rc = min(128, end - c0);
        const int arow = c0 + w * 16 + lr;
        const int arowc = min(arow, end - 1);

        // load x A-fragments (fp32 -> bf16 regs)
        bf16x8 af[4];
#pragma unroll
        for (int ks = 0; ks < 4; ++ks) {
            const float4* xp4 = (const float4*)(x + (size_t)arowc * 128 + ks * 32 + lk * 8);
            af[ks] = pack8(xp4[0], xp4[1]);
        }
        // xp GEMM
        f32x4 acc[8];
#pragma unroll
        for (int nr = 0; nr < 8; ++nr) acc[nr] = z4;
#pragma unroll
        for (int ks = 0; ks < 4; ++ks)
#pragma unroll
            for (int nr = 0; nr < 8; ++nr) {
                bf16x8 bfrag = *(const bf16x8*)&WbL[(nr * 16 + lr) * 68 + ks * 16 + lk * 4];
                acc[nr] = __builtin_amdgcn_mfma_f32_16x16x32_bf16(af[ks], bfrag, acc[nr], 0, 0, 0);
            }
        // bias + XP write (own 16 rows)
#pragma unroll
        for (int nr = 0; nr < 8; ++nr) {
            float bf = b_in[nr * 16 + lr];
#pragma unroll
            for (int r = 0; r < 4; ++r) {
                int row = w * 16 + lk * 4 + r;
                XPs[row * 136 + nr * 16 + lr] = f2bfu(((const float*)&acc[nr])[r] + bf);
            }
        }
        // re-load own XP rows as A-frags (same wave wrote them)
        bf16x8 xf[4];
#pragma unroll
        for (int ks = 0; ks < 4; ++ks)
            xf[ks] = *(const bf16x8*)&XPs[(w * 16 + lr) * 136 + ks * 32 + lk * 8];
        // score MFMA
        f32x4 sacc = z4;
#pragma unroll
        for (int ks = 0; ks < 4; ++ks) {
            bf16x8 bfrag = *(const bf16x8*)&WaL[lr * 68 + ks * 16 + lk * 4];
            sacc = __builtin_amdgcn_mfma_f32_16x16x32_bf16(xf[ks], bfrag, sacc, 0, 0, 0);
        }
        if (lr < A_HEADS) {
            float ba = b_a[lr];
#pragma unroll
            for (int r = 0; r < 4; ++r) {
                int row = w * 16 + lk * 4 + r;
                scoref[row * 8 + lr] = __expf(-fabsf(((const float*)&sacc)[r] + ba));
            }
        }
        // out_part GEMM: x half (Wo cols 0..63) + xp half (cols 64..127)
        f32x4 aco[4];
#pragma unroll
        for (int nr = 0; nr < 4; ++nr) aco[nr] = z4;
#pragma unroll
        for (int ks = 0; ks < 4; ++ks)
#pragma unroll
            for (int nr = 0; nr < 4; ++nr) {
                bf16x8 b0 = *(const bf16x8*)&WoL[(nr * 16 + lr) * 132 + ks * 16 + lk * 4];
                aco[nr] = __builtin_amdgcn_mfma_f32_16x16x32_bf16(af[ks], b0, aco[nr], 0, 0, 0);
                bf16x8 b1 = *(const bf16x8*)&WoL[(nr * 16 + lr) * 132 + 64 + ks * 16 + lk * 4];
                aco[nr] = __builtin_amdgcn_mfma_f32_16x16x32_bf16(xf[ks], b1, aco[nr], 0, 0, 0);
            }
        // store out_part (bf16, own rows)
#pragma unroll
        for (int nr = 0; nr < 4; ++nr)
#pragma unroll
            for (int r = 0; r < 4; ++r) {
                int n = c0 + w * 16 + lk * 4 + r;
                if (n < end)
                    out_part[(size_t)n * 64 + nr * 16 + lr] = f2bfu(((const float*)&aco[nr])[r]);
            }
        __syncthreads();   // XP + scoref visible to all waves

        // register-accumulated segment sum/max: thread = (a0, f-pair)
        for (int i = 0; i < rc; ++i) {
            unsigned u = XP[i * 68 + f2];
            float sa = scoref[i * 8 + a0];
            float e0 = sa * bfl(u), e1 = sa * bfh(u);
            sum0 += e0; sum1 += e1;
            mx0 = fmaxf(mx0, e0); mx1 = fmaxf(mx1, e1);
        }
        __syncthreads();   // protect XP/scoref before next chunk overwrites
    }

    // ---- finalize: agg vector (2048) into XPf, then projection ----
    const float inv = 1.f / (float)cnt;
    XPf[a0 * 256 + 2 * f2]       = sum0 * inv;
    XPf[a0 * 256 + 2 * f2 + 1]   = sum1 * inv;
    XPf[a0 * 256 + 128 + 2 * f2]     = mx0;
    XPf[a0 * 256 + 128 + 2 * f2 + 1] = mx1;
    __syncthreads();

#pragma unroll
    for (int i = 0; i < 8; ++i) {
        int o = w * 8 + i;
        const float* wrow = W_out + (size_t)o * H_DIM + 256;
        float partial = 0.f;
#pragma unroll
        for (int c = 0; c < 8; ++c) {
            int jj = c * 256 + l * 4;
            float4 wv = *(const float4*)&wrow[jj];
            float4 av = *(const float4*)&XPf[jj];
            partial = fmaf(wv.x, av.x, partial);
            partial = fmaf(wv.y, av.y, partial);
            partial = fmaf(wv.z, av.z, partial);
            partial = fmaf(wv.w, av.w, partial);
        }
#pragma unroll
        for (int m = 1; m < 64; m <<= 1) partial += __shfl_xor(partial, m);
        if (l == 0) agg_proj[b * D_OUTPUT + o] = partial + b_out[o];
    }
}

// -------- out = relu(out_part + agg_proj[batch]) — pure streaming -----------
__global__ __launch_bounds__(256) void out_final_kernel(
        const unsigned* __restrict__ out_part, const int* __restrict__ batch,
        const float* __restrict__ agg_proj, float* __restrict__ out) {
    int q = blockIdx.x * 256 + threadIdx.x;   // quad index: N*16 total
    if (q >= N_NODES * 16) return;
    int n = q >> 4, c4 = (q & 15) * 4;
    int bs = batch[n];
    uint2 v = *(const uint2*)(out_part + (size_t)n * 32 + (c4 >> 1));
    float4 ap = *(const float4*)(agg_proj + (size_t)bs * 64 + c4);
    float4 o;
    o.x = fmaxf(bfl(v.x) + ap.x, 0.f);
    o.y = fmaxf(bfh(v.x) + ap.y, 0.f);
    o.z = fmaxf(bfl(v.y) + ap.z, 0.f);
    o.w = fmaxf(bfh(v.y) + ap.w, 0.f);
    *(float4*)(out + (size_t)n * 64 + c4) = o;
}

extern "C" void kernel_launch(void* const* d_in, const int* in_sizes, int n_in,
                              void* d_out, int out_size, void* d_ws, size_t ws_size,
                              hipStream_t stream) {
    const float* x     = (const float*)d_in[0];
    const int*   batch = (const int*)d_in[1];
    const float* W_in  = (const float*)d_in[3];
    const float* b_in  = (const float*)d_in[4];
    const float* W_a   = (const float*)d_in[5];
    const float* b_a   = (const float*)d_in[6];
    const float* W_out = (const float*)d_in[7];
    const float* b_out = (const float*)d_in[8];
    float* out = (float*)d_out;

    float* agg_proj = (float*)d_ws;                          // 512*64 f32
    int* seg_start = (int*)(agg_proj + B_SEGS * D_OUTPUT);   // 513 (pad 520)
    unsigned short* out_part = (unsigned short*)(seg_start + 520); // N*64 u16
    unsigned* out_part_u32 = (unsigned*)out_part;

    seg_bounds_kernel<<<1, 1024, 0, stream>>>(batch, N_NODES, seg_start);
    mega_kernel<<<B_SEGS, 512, 0, stream>>>(
        x, seg_start, W_in, b_in, W_a, b_a, W_out, b_out, out_part, agg_proj);
    out_final_kernel<<<(N_NODES * 16 + 255) / 256, 256, 0, stream>>>(
        out_part_u32, batch, agg_proj, out);
}